// Round 16
// baseline (200.172 us; speedup 1.0000x reference)
//
#include <hip/hip_runtime.h>
#include <hip/hip_bf16.h>

#define DIM 768
#define HEADS 12
#define HD 64
#define SEQ 2048
#define BATCH 4
#define BHN 48          // BATCH*HEADS
#define TOK 8192        // BATCH*SEQ

#if __has_builtin(__builtin_amdgcn_exp2f)
#define EXP2F __builtin_amdgcn_exp2f
#else
#define EXP2F exp2f
#endif
// exp(s*0.125) = 2^(s * 0.125 * log2(e)); folded into Q at the QKV epilogue.
#define EXP_C 0.1803368801111244f

using short8  = __attribute__((ext_vector_type(8))) short;
using short4v = __attribute__((ext_vector_type(4))) short;
using float4v = __attribute__((ext_vector_type(4))) float;

__device__ __forceinline__ short f2b(float f) {
    union { float f; unsigned u; } v; v.f = f;
    unsigned r = v.u + 0x7FFF + ((v.u >> 16) & 1);
    return (short)(r >> 16);
}
__device__ __forceinline__ float b2f(short s) {
    union { unsigned u; float f; } v;
    v.u = ((unsigned)(unsigned short)s) << 16;
    return v.f;
}
// pack two floats to bf16x2 in ONE instruction (v_cvt_pk_bf16_f32, RNE).
__device__ __forceinline__ unsigned pk2(float a, float b) {
    unsigned r;
    asm("v_cvt_pk_bf16_f32 %0, %1, %2" : "=v"(r) : "v"(a), "v"(b));
    return r;
}

// async global->LDS copy, 16B per lane; LDS dest = uniform base + lane*16
typedef const __attribute__((address_space(1))) unsigned GU;
typedef __attribute__((address_space(3))) unsigned LU;
__device__ __forceinline__ void gload_lds16(const short* g, short* l) {
    __builtin_amdgcn_global_load_lds((GU*)g, (LU*)l, 16, 0, 0);
}

// ---------------- fp32 -> bf16 cast (+ Vsum zeroing), one launch ----------------
__global__ void cast_all(const float* __restrict__ x, const float* __restrict__ wq,
                         const float* __restrict__ wp,
                         short* __restrict__ xb, short* __restrict__ wqb,
                         short* __restrict__ wpb, float* __restrict__ Vsum,
                         int nx4, int nq4) {
    int i = blockIdx.x * 256 + threadIdx.x;
    if (i < BHN * 64) Vsum[i] = 0.f;
    const float* in; short* out; int j = i;
    if (i < nx4)            { in = x;  out = xb;  }
    else if (i < nx4 + nq4) { in = wq; out = wqb; j = i - nx4; }
    else                    { in = wp; out = wpb; j = i - nx4 - nq4; }
    float4 f = ((const float4*)in)[j];
    short4 o;
    o.x = f2b(f.x); o.y = f2b(f.y); o.z = f2b(f.z); o.w = f2b(f.w);
    ((short4*)out)[j] = o;
}

// ---------------- QKV GEMM, 128x128 tile, BK=32 ring-of-3 pipeline ----------------
__global__ __launch_bounds__(256, 3)
void gemm_qkv(const short* __restrict__ A, const short* __restrict__ Bw,
              short* __restrict__ Qw, short* __restrict__ Kw, short* __restrict__ Vw,
              float* __restrict__ Vsum)
{
    __shared__ __align__(16) short As[3][128 * 32];   // 24 KB
    __shared__ __align__(16) short Bs[3][128 * 32];   // 24 KB -> 48 KB total

    const int tid  = threadIdx.x;
    const int lane = tid & 63;
    const int wave = tid >> 6;
    const int wm = (wave >> 1) * 64, wn = (wave & 1) * 64;
    const int l15 = lane & 15, quad = lane >> 4;

    const int gid = blockIdx.x;
    const int w   = gid >> 3;
    const int ybl = (gid & 7) * 8 + (w & 7);   // 0..63 token block
    const int xbl = w >> 3;                    // 0..17 col block

    const bool vpart = (xbl >= 12);
    const short* rowsP = vpart ? (Bw + 1536 * 768) : A;   // Wv rows | x tokens
    const short* colsP = vpart ? A : Bw;                  // x tokens | W rows
    const int m0 = vpart ? (xbl - 12) * 128 : ybl * 128;
    const int n0 = vpart ? ybl * 128 : xbl * 128;
    const int K = DIM;

    float4v acc[4][4];
    #pragma unroll
    for (int i = 0; i < 4; i++)
        #pragma unroll
        for (int j = 0; j < 4; j++)
            acc[i][j] = (float4v){0.f, 0.f, 0.f, 0.f};

    const int G0 = wave * 128 + lane;
    const int G1 = G0 + 64;
    const int rA0 = G0 >> 2, cA0 = (G0 & 3) * 8;
    const int rA1 = G1 >> 2, cA1 = (G1 & 3) * 8;
    const int ldsoff = wave * 1024;

    // stage K-step t (32 cols) into ring buffer buf: 4 DMAs per wave
    auto STAGE = [&](int t, int buf) {
        const int kc = t * 32;
        gload_lds16(&rowsP[(size_t)(m0 + rA0) * K + kc + cA0], &As[buf][ldsoff]);
        gload_lds16(&rowsP[(size_t)(m0 + rA1) * K + kc + cA1], &As[buf][ldsoff + 512]);
        gload_lds16(&colsP[(size_t)(n0 + rA0) * K + kc + cA0], &Bs[buf][ldsoff]);
        gload_lds16(&colsP[(size_t)(n0 + rA1) * K + kc + cA1], &Bs[buf][ldsoff + 512]);
    };

    STAGE(0, 0);
    STAGE(1, 1);

    int cur = 0, nx2 = 2;
    for (int t = 0; t < 24; t++) {
        if (t < 23) { asm volatile("s_waitcnt vmcnt(4)" ::: "memory"); }
        else        { asm volatile("s_waitcnt vmcnt(0)" ::: "memory"); }
        __builtin_amdgcn_sched_barrier(0);
        __builtin_amdgcn_s_barrier();          // stage(t) resident; t-1 reads done
        __builtin_amdgcn_sched_barrier(0);

        short8 af[4], bfr[4];
        #pragma unroll
        for (int tt = 0; tt < 4; tt++) {
            af[tt]  = *(const short8*)&As[cur][(wm + tt * 16 + l15) * 32 + quad * 8];
            bfr[tt] = *(const short8*)&Bs[cur][(wn + tt * 16 + l15) * 32 + quad * 8];
        }
        #pragma unroll
        for (int tm = 0; tm < 4; tm++)
            #pragma unroll
            for (int tn = 0; tn < 4; tn++)
                acc[tm][tn] = __builtin_amdgcn_mfma_f32_16x16x32_bf16(af[tm], bfr[tn], acc[tm][tn], 0, 0, 0);

        if (t < 22) STAGE(t + 2, nx2);         // overwrite buffer last read at t-1
        cur = (cur == 2) ? 0 : cur + 1;
        nx2 = (nx2 == 2) ? 0 : nx2 + 1;
    }

    #pragma unroll
    for (int tm = 0; tm < 4; tm++)
        #pragma unroll
        for (int tn = 0; tn < 4; tn++)
            #pragma unroll
            for (int r = 0; r < 4; r++) {
                int row = m0 + wm + tm * 16 + quad * 4 + r;
                int col = n0 + wn + tn * 16 + l15;
                float v = acc[tm][tn][r];
                if (vpart) {
                    int hh = row >> 6, d = row & 63;
                    int b = col >> 11, n = col & 2047;
                    int bh = b * HEADS + hh;
                    int t2 = n >> 6, c2h = (n >> 5) & 1, wk = n & 31;
                    int slot = ((wk & 15) >> 2) * 8 + ((wk & 16) >> 2) + (wk & 3);
                    int g2 = c2h * 4 + (slot >> 3);
                    int gp2 = g2 ^ (d & 7);
                    Vw[(size_t)bh * (SEQ * 64) + t2 * 4096 + d * 64 + gp2 * 8 + (slot & 7)] = f2b(v);
                } else {
                    int hh = (col & 767) >> 6, d = col & 63;
                    int b = row >> 11, n = row & 2047;
                    int bh = b * HEADS + hh;
                    size_t idx = (size_t)bh * (SEQ * 64) + (size_t)n * 64
                               + (((d >> 3) ^ (n & 7)) << 3) + (d & 7);
                    if (col < 768) Qw[idx] = f2b(v * EXP_C);
                    else           Kw[idx] = f2b(v);
                }
            }

    // fused vsum: partial column sums over this block's 64 tokens (per wave-half)
    if (vpart) {
        const int bb = n0 >> 11;   // batch of this block's tokens
        #pragma unroll
        for (int tm = 0; tm < 4; tm++)
            #pragma unroll
            for (int r = 0; r < 4; r++) {
                float s4 = (acc[tm][0][r] + acc[tm][1][r]) + (acc[tm][2][r] + acc[tm][3][r]);
                #pragma unroll
                for (int m = 1; m < 16; m <<= 1) s4 += __shfl_xor(s4, m, 64);
                if (l15 == 0) {
                    int row = m0 + wm + tm * 16 + quad * 4 + r;
                    int hh = row >> 6, d = row & 63;
                    atomicAdd(&Vsum[(bb * HEADS + hh) * 64 + d], s4);
                }
            }
    }
}

// ---------------- proj GEMM, 128x64 tile, BK=32 ring-of-3 pipeline ----------------
__global__ __launch_bounds__(256, 4)
void gemm_proj(const short* __restrict__ A, const short* __restrict__ Bw,
               const float* __restrict__ bias, float* __restrict__ Out)
{
    __shared__ __align__(16) short As[3][128 * 32];   // 24 KB
    __shared__ __align__(16) short Bs[3][64 * 32];    // 12 KB -> 36 KB total

    const int tid  = threadIdx.x;
    const int lane = tid & 63;
    const int wave = tid >> 6;
    const int wm = (wave >> 1) * 64, wn = (wave & 1) * 32;
    const int l15 = lane & 15, quad = lane >> 4;

    const int gid = blockIdx.x;             // 0..767
    const int w   = gid >> 3;               // 0..95
    const int ybl = (gid & 7) * 8 + (w & 7);   // 0..63 token block
    const int xbl = w >> 3;                    // 0..11 col block
    const int m0 = ybl * 128, n0 = xbl * 64;
    const int K = DIM;

    float4v acc[4][2];
    #pragma unroll
    for (int i = 0; i < 4; i++)
        #pragma unroll
        for (int j = 0; j < 2; j++)
            acc[i][j] = (float4v){0.f, 0.f, 0.f, 0.f};

    const int GA0 = wave * 128 + lane, GA1 = GA0 + 64;
    const int rA0 = GA0 >> 2, cA0 = (GA0 & 3) * 8;
    const int rA1 = GA1 >> 2, cA1 = (GA1 & 3) * 8;
    const int GB0 = wave * 64 + lane;
    const int rB0 = GB0 >> 2, cB0 = (GB0 & 3) * 8;
    const int ldsoffA = wave * 1024, ldsoffB = wave * 512;

    // stage K-step t into ring buffer buf: 3 DMAs per wave (2 A + 1 B)
    auto STAGE = [&](int t, int buf) {
        const int kc = t * 32;
        gload_lds16(&A [(size_t)(m0 + rA0) * K + kc + cA0], &As[buf][ldsoffA]);
        gload_lds16(&A [(size_t)(m0 + rA1) * K + kc + cA1], &As[buf][ldsoffA + 512]);
        gload_lds16(&Bw[(size_t)(n0 + rB0) * K + kc + cB0], &Bs[buf][ldsoffB]);
    };

    STAGE(0, 0);
    STAGE(1, 1);

    int cur = 0, nx2 = 2;
    for (int t = 0; t < 24; t++) {
        if (t < 23) { asm volatile("s_waitcnt vmcnt(3)" ::: "memory"); }
        else        { asm volatile("s_waitcnt vmcnt(0)" ::: "memory"); }
        __builtin_amdgcn_sched_barrier(0);
        __builtin_amdgcn_s_barrier();
        __builtin_amdgcn_sched_barrier(0);

        short8 af[4], bfr[2];
        #pragma unroll
        for (int tt = 0; tt < 4; tt++)
            af[tt] = *(const short8*)&As[cur][(wm + tt * 16 + l15) * 32 + quad * 8];
        #pragma unroll
        for (int tt = 0; tt < 2; tt++)
            bfr[tt] = *(const short8*)&Bs[cur][(wn + tt * 16 + l15) * 32 + quad * 8];
        #pragma unroll
        for (int tm = 0; tm < 4; tm++)
            #pragma unroll
            for (int tn = 0; tn < 2; tn++)
                acc[tm][tn] = __builtin_amdgcn_mfma_f32_16x16x32_bf16(af[tm], bfr[tn], acc[tm][tn], 0, 0, 0);

        if (t < 22) STAGE(t + 2, nx2);
        cur = (cur == 2) ? 0 : cur + 1;
        nx2 = (nx2 == 2) ? 0 : nx2 + 1;
    }

    #pragma unroll
    for (int tm = 0; tm < 4; tm++)
        #pragma unroll
        for (int tn = 0; tn < 2; tn++)
            #pragma unroll
            for (int r = 0; r < 4; r++) {
                int row = m0 + wm + tm * 16 + quad * 4 + r;
                int col = n0 + wn + tn * 16 + l15;
                Out[(size_t)row * 768 + col] = acc[tm][tn][r] + bias[col];
            }
}

// ---------------- fused double-softmax attention ----------------
// Round-26: 2x2 wave split. wave = (q-half: 64 rows) x (key-half: 32 keys).
// Each wave reads only HALF the K tile and HALF the V tile per kt
// (8 ds_read_b128 instead of 16) -> per-CU LDS demand halves (31->15.5 us),
// while MFMA/VALU work per wave is conserved (36 MFMAs, 32 exps; nb 2->4).
// Occupancy unchanged: 48 KB ring -> 3 blocks/CU, VGPR target <=170 (bounds 3).
// Epilogue: partner waves (key-halves) pair-sum Aacc/Lacc via LDS.
__global__ __launch_bounds__(256, 3)
void attn_kernel(const short* __restrict__ Qw, const short* __restrict__ Kw,
                 const short* __restrict__ Vw, const float* __restrict__ Vsum,
                 short* __restrict__ Ow)
{
    __shared__ __align__(16) short LDS[24576];  // 48 KB: K[3][4096] | V[3][4096]; epi: float scratch

    const int tid  = threadIdx.x;
    const int lane = tid & 63, wave = tid >> 6;
    const int l15 = lane & 15, quad = lane >> 4;
    const int r7  = l15 & 7;
    // XCD-locality: 6 heads per XCD; the 16 q-blocks of a head share its K/V in L2.
    const int bid = blockIdx.x;
    const int ii  = bid >> 3;                  // 0..95
    const int bh  = (bid & 7) * 6 + (ii >> 4); // head
    const int qt  = ii & 15;                   // q-tile index
    const int qh  = wave >> 1;                 // q-half (0: rows 0-63, 1: rows 64-127)
    const int kh  = wave & 1;                  // key-half = this wave's c2
    const int wq  = qh * 64;

    const short* Qp = Qw + (size_t)bh * (SEQ * 64) + qt * 8192;
    const short* Kp = Kw + (size_t)bh * (SEQ * 64);
    const short* Vp = Vw + (size_t)bh * (SEQ * 64);

    // ones B-fragment for 16x16x32: col 0 only (l15==0), all 8 k-slots = 1.0
    short8 onesf;
    #pragma unroll
    for (int j = 0; j < 8; j++) onesf[j] = (l15 == 0) ? (short)0x3F80 : (short)0;

    // ---- stage Q tile image (16 granules), read fragments, then free the LDS ----
    #pragma unroll
    for (int h = 0; h < 4; h++) {
        const int g = wave * 4 + h;
        gload_lds16(&Qp[g * 512 + lane * 8], &LDS[g * 512]);
    }
    __syncthreads();   // full drain ok here (prologue only)
    short8 aq[4][2];
    #pragma unroll
    for (int nb = 0; nb < 4; nb++)
        #pragma unroll
        for (int kk = 0; kk < 2; kk++) {
            int r = wq + nb * 16 + l15;
            aq[nb][kk] = *(const short8*)&LDS[r * 64 + (((kk * 4 + quad) ^ r7) << 3)];
        }
    __syncthreads();   // all waves done reading Q before K/V staging overwrites

    float4v Aacc[4][4], Lacc[4];
    #pragma unroll
    for (int nb = 0; nb < 4; nb++) {
        Lacc[nb] = (float4v){0.f, 0.f, 0.f, 0.f};
        #pragma unroll
        for (int t = 0; t < 4; t++) Aacc[nb][t] = (float4v){0.f, 0.f, 0.f, 0.f};
    }

    // stage(t2) -> buffer kbuf: 2 K-granules + 2 V-granules per wave (4 DMAs)
    auto STAGE = [&](int t2, int kbuf) {
        const int kb = kbuf * 4096;
        #pragma unroll
        for (int h = 0; h < 2; h++) {
            const int g = wave * 2 + h;
            gload_lds16(&Kp[(size_t)t2 * 4096 + g * 512 + lane * 8], &LDS[kb + g * 512]);
            gload_lds16(&Vp[(size_t)t2 * 4096 + g * 512 + lane * 8], &LDS[12288 + kb + g * 512]);
        }
    };

    STAGE(0, 0);
    STAGE(1, 1);

    int cur = 0, nx2 = 2;   // kt%3 and (kt+2)%3
    for (int kt = 0; kt < 32; kt++) {
        if (kt < 31) { asm volatile("s_waitcnt vmcnt(4)" ::: "memory"); }
        else         { asm volatile("s_waitcnt vmcnt(0)" ::: "memory"); }
        __builtin_amdgcn_sched_barrier(0);
        __builtin_amdgcn_s_barrier();          // stage(kt) resident; kt-1 reads done
        __builtin_amdgcn_sched_barrier(0);

        const short* KB = &LDS[cur * 4096];
        const short* VB = &LDS[12288 + cur * 4096];
        const int c2 = kh;                     // this wave's fixed 32-key half

        union AE { unsigned u[4]; short8 s; };
        AE ae[4];
        #pragma unroll
        for (int tn2 = 0; tn2 < 2; tn2++) {
            const int row = (c2 * 2 + tn2) * 16 + l15;
            const short* rp = &KB[row * 64];
            short8 b0 = *(const short8*)&rp[(quad ^ r7) << 3];
            short8 b1 = *(const short8*)&rp[((4 + quad) ^ r7) << 3];
            #pragma unroll
            for (int nb = 0; nb < 4; nb++) {
                float4v s = (float4v){0.f, 0.f, 0.f, 0.f};
                s = __builtin_amdgcn_mfma_f32_16x16x32_bf16(b0, aq[nb][0], s, 0, 0, 0);
                s = __builtin_amdgcn_mfma_f32_16x16x32_bf16(b1, aq[nb][1], s, 0, 0, 0);
                ae[nb].u[tn2 * 2]     = pk2(EXP2F(s[0]), EXP2F(s[1]));
                ae[nb].u[tn2 * 2 + 1] = pk2(EXP2F(s[2]), EXP2F(s[3]));
            }
        }
        __builtin_amdgcn_s_setprio(1);
        #pragma unroll
        for (int nb = 0; nb < 4; nb++)
            Lacc[nb] = __builtin_amdgcn_mfma_f32_16x16x32_bf16(ae[nb].s, onesf, Lacc[nb], 0, 0, 0);
        #pragma unroll
        for (int tn = 0; tn < 4; tn++) {
            const int d = tn * 16 + l15;
            short8 bv = *(const short8*)&VB[d * 64 + (((c2 * 4 + quad) ^ r7) << 3)];
            #pragma unroll
            for (int nb = 0; nb < 4; nb++)
                Aacc[nb][tn] = __builtin_amdgcn_mfma_f32_16x16x32_bf16(ae[nb].s, bv, Aacc[nb][tn], 0, 0, 0);
        }
        __builtin_amdgcn_s_setprio(0);

        if (kt < 30) STAGE(kt + 2, nx2);       // overwrite buffer last read at kt-1
        cur = (cur == 2) ? 0 : cur + 1;
        nx2 = (nx2 == 2) ? 0 : nx2 + 1;
    }

    // ---- pair-sum epilogue: kh==1 writes partials; kh==0 adds and stores ----
    __syncthreads();
    float* ldsf = (float*)LDS;
    const int ebase = qh * 5120;               // 20 KB per q-half region (floats)
    if (kh == 1) {
        #pragma unroll
        for (int nb = 0; nb < 4; nb++) {
            #pragma unroll
            for (int tn = 0; tn < 4; tn++)
                #pragma unroll
                for (int r = 0; r < 4; r++)
                    ldsf[ebase + (nb * 16 + tn * 4 + r) * 64 + lane] = Aacc[nb][tn][r];
            #pragma unroll
            for (int r = 0; r < 4; r++)
                ldsf[ebase + 4096 + (nb * 4 + r) * 64 + lane] = Lacc[nb][r];
        }
    }
    __syncthreads();
    if (kh == 0) {
        const int b = bh / HEADS, hh = bh - (bh / HEADS) * HEADS;
        #pragma unroll
        for (int nb = 0; nb < 4; nb++) {
            float il[4];
            #pragma unroll
            for (int r = 0; r < 4; r++) {
                float ls = Lacc[nb][r] + ldsf[ebase + 4096 + (nb * 4 + r) * 64 + lane];
                il[r] = 1.f / __shfl(ls, lane & 48, 64);
            }
            #pragma unroll
            for (int r = 0; r < 4; r++) {
                int row = qt * 128 + wq + nb * 16 + quad * 4 + r;
                int tok = b * SEQ + row;
                #pragma unroll
                for (int tn = 0; tn < 4; tn++) {
                    int d = tn * 16 + l15;
                    float a = Aacc[nb][tn][r] + ldsf[ebase + (nb * 16 + tn * 4 + r) * 64 + lane];
                    float vs = Vsum[bh * 64 + d];
                    float val = (vs + a * il[r]) * (1.f / 2049.f);
                    Ow[(size_t)tok * 768 + hh * 64 + d] = f2b(val);
                }
            }
        }
    }
}

extern "C" void kernel_launch(void* const* d_in, const int* in_sizes, int n_in,
                              void* d_out, int out_size, void* d_ws, size_t ws_size,
                              hipStream_t stream) {
    const float* x      = (const float*)d_in[0];
    const float* w_qkv  = (const float*)d_in[1];
    const float* w_proj = (const float*)d_in[2];
    const float* b_proj = (const float*)d_in[3];
    float* out = (float*)d_out;

    char* ws = (char*)d_ws;
    size_t off = 0;
    auto alloc = [&](size_t bytes) {
        void* p = ws + off;
        off += (bytes + 255) & ~(size_t)255;
        return p;
    };
    short* x_bf  = (short*)alloc((size_t)TOK * DIM * 2);
    short* wq_bf = (short*)alloc((size_t)3 * DIM * DIM * 2);
    short* wp_bf = (short*)alloc((size_t)DIM * DIM * 2);
    short* Qw    = (short*)alloc((size_t)BHN * SEQ * 64 * 2);
    short* Kw    = (short*)alloc((size_t)BHN * SEQ * 64 * 2);
    short* Vw    = (short*)alloc((size_t)BHN * SEQ * 64 * 2);
    short* Ow    = (short*)alloc((size_t)TOK * DIM * 2);
    float* Vsum  = (float*)alloc((size_t)BHN * 64 * 4);

    int nx4 = TOK * DIM / 4, nq4 = 3 * DIM * DIM / 4, np4 = DIM * DIM / 4;
    int tot4 = nx4 + nq4 + np4;
    cast_all<<<tot4 / 256, 256, 0, stream>>>(x, w_qkv, w_proj, x_bf, wq_bf, wp_bf, Vsum, nx4, nq4);

    gemm_qkv<<<1152, 256, 0, stream>>>(x_bf, wq_bf, Qw, Kw, Vw, Vsum);

    attn_kernel<<<BHN * 16, 256, 0, stream>>>(Qw, Kw, Vw, Vsum, Ow);

    gemm_proj<<<768, 256, 0, stream>>>(Ow, wp_bf, b_proj, out);
}